// Round 16
// baseline (393.478 us; speedup 1.0000x reference)
//
#include <hip/hip_runtime.h>
#include <stdint.h>

#define D_MODEL 1024
#define HIDDEN  4096
#define SEQ     2048
#define NTOK    8192
#define NHEAD   16
#define HDIM    64

typedef unsigned short u16;
typedef __attribute__((ext_vector_type(8))) __bf16 bf16x8;
typedef __attribute__((ext_vector_type(4))) float f32x4;

__device__ __forceinline__ u16 f2bf(float f) {
  union { float f; unsigned u; } c; c.f = f;
  unsigned u = c.u + 0x7fffu + ((c.u >> 16) & 1u);
  return (u16)(u >> 16);
}

__device__ __forceinline__ float bf2f(u16 u) {
  union { unsigned u; float f; } c; c.u = (unsigned)u << 16;
  return c.f;
}

__device__ __forceinline__ void gload16(const void* g, void* l) {
  __builtin_amdgcn_global_load_lds((const __attribute__((address_space(1))) void*)g,
                                   (__attribute__((address_space(3))) void*)l, 16, 0, 0);
}

// ---------------- weight convert+transpose: 4x [1024][1024] f32 -> [1024][1024] bf16^T ----
__global__ void transpose_cvt4(const float* __restrict__ A0, const float* __restrict__ A1,
                               const float* __restrict__ A2, const float* __restrict__ A3,
                               u16* __restrict__ O) {
  __shared__ float t[32][33];
  const int z = blockIdx.z;
  const float* W = (z == 0) ? A0 : (z == 1) ? A1 : (z == 2) ? A2 : A3;
  u16* Wt = O + ((size_t)z << 20);
  const int k0 = blockIdx.y * 32, n0 = blockIdx.x * 32;
  const int tx = threadIdx.x, ty = threadIdx.y;  // 32 x 8
#pragma unroll
  for (int p = 0; p < 4; ++p)
    t[ty + p * 8][tx] = W[(size_t)(k0 + ty + p * 8) * D_MODEL + n0 + tx];
  __syncthreads();
#pragma unroll
  for (int p = 0; p < 4; ++p) {
    const int n = ty + p * 8;
    Wt[(size_t)(n0 + n) * D_MODEL + k0 + tx] = f2bf(t[tx][n]);
  }
}

// ---------------- weight convert + transpose: W[K][N] f32 -> Wt[N][K] bf16 ----------------
__global__ void transpose_cvt(const float* __restrict__ W, u16* __restrict__ Wt, int K, int N) {
  __shared__ float t[32][33];
  const int k0 = blockIdx.y * 32, n0 = blockIdx.x * 32;
  const int tx = threadIdx.x, ty = threadIdx.y;  // 32 x 8
#pragma unroll
  for (int p = 0; p < 4; ++p)
    t[ty + p * 8][tx] = W[(size_t)(k0 + ty + p * 8) * N + n0 + tx];
  __syncthreads();
#pragma unroll
  for (int p = 0; p < 4; ++p) {
    const int n = ty + p * 8;
    Wt[(size_t)(n0 + n) * K + k0 + tx] = f2bf(t[tx][n]);
  }
}

// ---------------- LayerNorm (f32 in): x f32 [NTOK][D] -> xn bf16 ----------------
__global__ __launch_bounds__(256)
void ln_kernel(const float* __restrict__ x, const float* __restrict__ gamma,
               const float* __restrict__ beta, u16* __restrict__ out) {
  const int row = blockIdx.x;
  const int tid = threadIdx.x;
  const float4 v = ((const float4*)(x + (size_t)row * D_MODEL))[tid];
  float s = v.x + v.y + v.z + v.w;
  float q = v.x * v.x + v.y * v.y + v.z * v.z + v.w * v.w;
#pragma unroll
  for (int o = 32; o > 0; o >>= 1) { s += __shfl_down(s, o); q += __shfl_down(q, o); }
  __shared__ float ps[4], pq[4];
  const int wid = tid >> 6, lane = tid & 63;
  if (lane == 0) { ps[wid] = s; pq[wid] = q; }
  __syncthreads();
  s = ps[0] + ps[1] + ps[2] + ps[3];
  q = pq[0] + pq[1] + pq[2] + pq[3];
  const float mean = s * (1.0f / D_MODEL);
  const float var = q * (1.0f / D_MODEL) - mean * mean;
  const float rstd = rsqrtf(var + 1e-10f);
  const float4 gv = ((const float4*)gamma)[tid];
  const float4 bv = ((const float4*)beta)[tid];
  ushort4 o4;
  o4.x = f2bf((v.x - mean) * rstd * gv.x + bv.x);
  o4.y = f2bf((v.y - mean) * rstd * gv.y + bv.y);
  o4.z = f2bf((v.z - mean) * rstd * gv.z + bv.z);
  o4.w = f2bf((v.w - mean) * rstd * gv.w + bv.w);
  ((ushort4*)(out + (size_t)row * D_MODEL))[tid] = o4;
}

// ---------------- LayerNorm (bf16 in): x1b bf16 [NTOK][D] -> xn bf16 ----------------
__global__ __launch_bounds__(256)
void ln_kernel_b(const u16* __restrict__ x, const float* __restrict__ gamma,
                 const float* __restrict__ beta, u16* __restrict__ out) {
  const int row = blockIdx.x;
  const int tid = threadIdx.x;
  const ushort4 uv = ((const ushort4*)(x + (size_t)row * D_MODEL))[tid];
  const float v0 = bf2f(uv.x), v1 = bf2f(uv.y), v2 = bf2f(uv.z), v3 = bf2f(uv.w);
  float s = v0 + v1 + v2 + v3;
  float q = v0 * v0 + v1 * v1 + v2 * v2 + v3 * v3;
#pragma unroll
  for (int o = 32; o > 0; o >>= 1) { s += __shfl_down(s, o); q += __shfl_down(q, o); }
  __shared__ float ps[4], pq[4];
  const int wid = tid >> 6, lane = tid & 63;
  if (lane == 0) { ps[wid] = s; pq[wid] = q; }
  __syncthreads();
  s = ps[0] + ps[1] + ps[2] + ps[3];
  q = pq[0] + pq[1] + pq[2] + pq[3];
  const float mean = s * (1.0f / D_MODEL);
  const float var = q * (1.0f / D_MODEL) - mean * mean;
  const float rstd = rsqrtf(var + 1e-10f);
  const float4 gv = ((const float4*)gamma)[tid];
  const float4 bv = ((const float4*)beta)[tid];
  ushort4 o4;
  o4.x = f2bf((v0 - mean) * rstd * gv.x + bv.x);
  o4.y = f2bf((v1 - mean) * rstd * gv.y + bv.y);
  o4.z = f2bf((v2 - mean) * rstd * gv.z + bv.z);
  o4.w = f2bf((v3 - mean) * rstd * gv.w + bv.w);
  ((ushort4*)(out + (size_t)row * D_MODEL))[tid] = o4;
}

// ---------------- gemm64: m97 structure, 128x128 tile, BK=64, 4 blocks/CU ----------------
// EPI 0: bf16 out, col bias.     EPI 1: f32 out += f32 res, col bias.
// EPI 2: gelu(erf)->bf16.  EPI 3: bf16, ROW bias, kv-permuted cols (V^T).
// EPI 6: fused QK dual output.  EPI 7: bf16 out = acc + bias + f32 res.
// EPI 8: f32 out = acc + bias + bf16 res.
template <int EPI, int KPY, int KPX>
__global__ __launch_bounds__(256, 4)
void gemm64(const u16* __restrict__ A, const u16* __restrict__ Bt,
            const float* __restrict__ bias, const float* __restrict__ bias2,
            const float* __restrict__ res, void* __restrict__ outp, void* __restrict__ outp2,
            int M, int N, int K) {
  __shared__ u16 As[128 * 64];
  __shared__ u16 Bs[128 * 64];
  const int tid = threadIdx.x;
  const int wid = tid >> 6, lane = tid & 63;
  const int g = lane >> 4, lr = lane & 15;
  const int wm = (wid & 1) << 6, wn = (wid >> 1) << 6;

  const int xcd = blockIdx.x & 7, l = blockIdx.x >> 3;
  int bx, by;
  if (KPY > 0) { by = xcd * KPY + (l % KPY); bx = l / KPY; }
  else         { bx = xcd * KPX + (l % KPX); by = l / KPX; }
  const int m0 = by * 128, n0 = bx * 128;

  const int NT = K >> 6;

  const int r0 = tid >> 3;
  const int csw = ((tid & 7) ^ (r0 & 7)) << 3;
  const u16* pA[4];
  const u16* pB[4];
#pragma unroll
  for (int i = 0; i < 4; ++i) {
    pA[i] = A + (size_t)(m0 + r0 + i * 32) * K + csw;
    pB[i] = Bt + (size_t)(n0 + r0 + i * 32) * K + csw;
  }
  const int db = (tid & 192) * 16;

  f32x4 acc[4][4] = {};

  for (int t = 0; t < NT; ++t) {
    __syncthreads();
#pragma unroll
    for (int i = 0; i < 4; ++i) {
      gload16(pA[i], (char*)As + db + i * 4096);
      gload16(pB[i], (char*)Bs + db + i * 4096);
      pA[i] += 64; pB[i] += 64;
    }
    __syncthreads();

#pragma unroll
    for (int ks = 0; ks < 2; ++ks) {
      bf16x8 af[4], bfr[4];
#pragma unroll
      for (int f = 0; f < 4; ++f) {
        const int ra = wm + f * 16 + lr;
        const int rb = wn + f * 16 + lr;
        const int co = ((ks * 4 + g) ^ (lr & 7)) * 8;
        af[f] = *(const bf16x8*)(As + ra * 64 + co);
        bfr[f] = *(const bf16x8*)(Bs + rb * 64 + co);
      }
      __builtin_amdgcn_s_setprio(1);
#pragma unroll
      for (int mf = 0; mf < 4; ++mf)
#pragma unroll
        for (int nf = 0; nf < 4; ++nf)
          acc[mf][nf] =
              __builtin_amdgcn_mfma_f32_16x16x32_bf16(af[mf], bfr[nf], acc[mf][nf], 0, 0, 0);
      __builtin_amdgcn_s_setprio(0);
    }
  }

  // ---- epilogue ----
#pragma unroll
  for (int mf = 0; mf < 4; ++mf)
#pragma unroll
    for (int nf = 0; nf < 4; ++nf) {
      const int gn = n0 + wn + nf * 16 + lr;
      const int gm = m0 + wm + mf * 16 + 4 * g;
#pragma unroll
      for (int r = 0; r < 4; ++r) {
        const float av = acc[mf][nf][r];
        if (EPI == 0) {
          ((u16*)outp)[(size_t)(gm + r) * N + gn] = f2bf(av + bias[gn]);
        } else if (EPI == 1) {
          const size_t idx = (size_t)(gm + r) * N + gn;
          ((float*)outp)[idx] = av + bias[gn] + res[idx];
        } else if (EPI == 2) {
          const float v = av + bias[gn];
          ((u16*)outp)[(size_t)(gm + r) * N + gn] =
              f2bf(0.5f * v * (1.0f + erff(v * 0.7071067811865475f)));
        } else if (EPI == 3) {
          const int gn_p = (gn & ~63) | ((gn & 15) << 2) | ((gn >> 4) & 3);
          ((u16*)outp)[(size_t)(gm + r) * N + gn_p] = f2bf(av + bias[gm + r]);
        } else if (EPI == 6) {
          const int side = gn >> 10, col = gn & 1023;
          u16* o = (u16*)(side ? outp2 : outp);
          float t_ = av + (side ? bias2[col] : bias[col]);
          if (!side) t_ *= 0.18033688011112042f;
          o[(size_t)(gm + r) * 1024 + col] = f2bf(t_);
        } else if (EPI == 7) {
          const size_t idx = (size_t)(gm + r) * N + gn;
          ((u16*)outp)[idx] = f2bf(av + bias[gn] + res[idx]);
        } else {  // EPI 8: f32 out = acc + bias + bf16 residual
          const size_t idx = (size_t)(gm + r) * N + gn;
          ((float*)outp)[idx] = av + bias[gn] + bf2f(((const u16*)res)[idx]);
        }
      }
    }
}

// ---------------- gemm256p v3: 256x256 8-phase, BK=64, template-faithful staging ---------
// All 12 fragment ds_reads at P1/P5 (regions read-retired before any stage touches them);
// exactly ONE 2-load half-tile staged per phase; VM6 at P4/P8 retires loads 3 phases old.
// sched_barrier(0) pins phase boundaries (rule #18).
template <int MH, int NH>
__device__ __forceinline__ void mmq(f32x4 (&acc)[8][4], const bf16x8 (&av)[4][2],
                                    const bf16x8 (&bv)[2][2]) {
  __builtin_amdgcn_s_setprio(1);
#pragma unroll
  for (int f = 0; f < 4; ++f)
#pragma unroll
    for (int n = 0; n < 2; ++n)
#pragma unroll
      for (int ks = 0; ks < 2; ++ks)
        acc[MH * 4 + f][NH * 2 + n] = __builtin_amdgcn_mfma_f32_16x16x32_bf16(
            av[f][ks], bv[n][ks], acc[MH * 4 + f][NH * 2 + n], 0, 0, 0);
  __builtin_amdgcn_s_setprio(0);
}

template <int EPI, int KPY, int KPX>
__global__ __launch_bounds__(512, 1)
void gemm256p(const u16* __restrict__ A, const u16* __restrict__ Bt,
              const float* __restrict__ bias, const float* __restrict__ res,
              void* __restrict__ outp, int M, int N, int K) {
  __shared__ u16 Ls[65536];  // 128 KB
  const int tid = threadIdx.x;
  const int wid = tid >> 6, lane = tid & 63;
  const int g = lane >> 4, lr = lane & 15;
  const int wm = wid >> 2, wn = wid & 3;

  const int xcd = blockIdx.x & 7, l = blockIdx.x >> 3;
  int bx, by;
  if (KPY > 0) { by = xcd * KPY + (l % KPY); bx = l / KPY; }
  else         { bx = xcd * KPX + (l % KPX); by = l / KPX; }
  const int m0 = by * 256, n0 = bx * 256;

  const int NT = K >> 6;

  const int r0 = tid >> 3;
  const int cc0 = ((tid & 7) ^ (r0 & 7)) << 3;
  const u16* Abase = A + (size_t)(m0 + r0) * K + cc0;
  const u16* Bbase = Bt + (size_t)(n0 + r0) * K + cc0;
  const int dstb = wid << 10;

  auto sA = [&](int d, int h, int tk) {
    const u16* p = Abase + (size_t)(h * 128) * K + tk * 64;
    char* q_ = (char*)Ls + d * 65536 + h * 16384 + dstb;
    gload16(p, q_);
    gload16(p + (size_t)64 * K, q_ + 8192);
  };
  auto sB = [&](int d, int h, int tk) {
    const u16* p = Bbase + (size_t)(h * 128) * K + tk * 64;
    char* q_ = (char*)Ls + d * 65536 + 32768 + h * 16384 + dstb;
    gload16(p, q_);
    gload16(p + (size_t)64 * K, q_ + 8192);
  };

  const int cof0 = ((g) ^ (lr & 7)) << 3;
  const int cof1 = ((4 | g) ^ (lr & 7)) << 3;
  const int aB = wm * 8192 + lr * 64;
  const int bB = 16384 + (wn >> 1) * 8192 + (wn & 1) * 4096 + lr * 64;

  f32x4 acc[8][4] = {};
  bf16x8 a[4][2], a2[4][2], b[2][2], b2[2][2];

  auto rdA = [&](bf16x8 (&dst)[4][2], int D, int mh) {
#pragma unroll
    for (int f = 0; f < 4; ++f) {
      dst[f][0] = *(const bf16x8*)(Ls + D + aB + (mh * 4 + f) * 1024 + cof0);
      dst[f][1] = *(const bf16x8*)(Ls + D + aB + (mh * 4 + f) * 1024 + cof1);
    }
  };
  auto rdB = [&](bf16x8 (&dst)[2][2], int D, int nh) {
#pragma unroll
    for (int f = 0; f < 2; ++f) {
      dst[f][0] = *(const bf16x8*)(Ls + D + bB + (nh * 2 + f) * 1024 + cof0);
      dst[f][1] = *(const bf16x8*)(Ls + D + bB + (nh * 2 + f) * 1024 + cof1);
    }
  };

#define BARR __builtin_amdgcn_s_barrier()
#define SCB0 __builtin_amdgcn_sched_barrier(0)
#define LG0 asm volatile("s_waitcnt lgkmcnt(0)" ::: "memory")
#define VM6 asm volatile("s_waitcnt vmcnt(6)" ::: "memory")
#define VM0 asm volatile("s_waitcnt vmcnt(0)" ::: "memory")

  // prologue: tile0 full (8 loads) + tile1 {B.h0, A.h0, A.h1} (6 loads)
  sA(0, 0, 0); sA(0, 1, 0); sB(0, 0, 0); sB(0, 1, 0);
  sB(1, 0, 1); sA(1, 0, 1); sA(1, 1, 1);
  VM6;  // retire tile0's 8; tile1's 6 in flight
  BARR; SCB0;

  for (int T = 0; T < NT; T += 2) {
    const bool s2 = (T + 2) < NT;  // NT even: also guards T+3
    // ---- tile T (D0) ----
    rdA(a, 0, 0); rdB(b, 0, 0); rdA(a2, 0, 1); rdB(b2, 0, 1);  // 12 ds_reads
    sB(1, 1, T + 1);                                            // P1
    BARR; LG0; SCB0; mmq<0, 0>(acc, a, b); BARR; SCB0;
    if (s2) sB(0, 0, T + 2);                                    // P2
    BARR; SCB0; mmq<1, 0>(acc, a2, b); BARR; SCB0;
    if (s2) sA(0, 0, T + 2);                                    // P3
    BARR; SCB0; mmq<1, 1>(acc, a2, b2); BARR; SCB0;
    if (s2) { sA(0, 1, T + 2); VM6; } else VM0;                 // P4
    SCB0; BARR; SCB0; mmq<0, 1>(acc, a, b2); BARR; SCB0;
    // ---- tile T+1 (D1) ----
    rdA(a, 32768, 0); rdB(b, 32768, 0); rdA(a2, 32768, 1); rdB(b2, 32768, 1);
    if (s2) sB(0, 1, T + 2);                                    // P5
    BARR; LG0; SCB0; mmq<0, 0>(acc, a, b); BARR; SCB0;
    if (s2) sB(1, 0, T + 3);                                    // P6
    BARR; SCB0; mmq<1, 0>(acc, a2, b); BARR; SCB0;
    if (s2) sA(1, 0, T + 3);                                    // P7
    BARR; SCB0; mmq<1, 1>(acc, a2, b2); BARR; SCB0;
    if (s2) { sA(1, 1, T + 3); VM6; } else VM0;                 // P8
    SCB0; BARR; SCB0; mmq<0, 1>(acc, a, b2); BARR; SCB0;
  }
#undef BARR
#undef SCB0
#undef LG0
#undef VM6
#undef VM0

  // ---- epilogue ----
#pragma unroll
  for (int mf = 0; mf < 8; ++mf)
#pragma unroll
    for (int nf = 0; nf < 4; ++nf) {
      const int gn = n0 + wn * 64 + nf * 16 + lr;
      const int gm = m0 + wm * 128 + mf * 16 + 4 * g;
      const float bb = bias[gn];
#pragma unroll
      for (int r = 0; r < 4; ++r) {
        const float av = acc[mf][nf][r];
        if (EPI == 1) {
          const size_t idx = (size_t)(gm + r) * N + gn;
          ((float*)outp)[idx] = av + bb + res[idx];
        } else {  // EPI 2: gelu
          const float v = av + bb;
          ((u16*)outp)[(size_t)(gm + r) * N + gn] =
              f2bf(0.5f * v * (1.0f + erff(v * 0.7071067811865475f)));
        }
      }
    }
}

// ---------------- flash attention v5 (round-11/13 proven, 91.7 us) ----------------
__global__ __launch_bounds__(256, 4)
void attn_kernel(const u16* __restrict__ Q, const u16* __restrict__ K,
                 const u16* __restrict__ Vt, u16* __restrict__ ctxo) {
  const int L = blockIdx.x;
  const int q0 = ((L >> 3) & 15) * 128;
  const int bh = ((L >> 7) << 3) | (L & 7);
  const int b = bh >> 4, h = bh & 15;
  const int tid = threadIdx.x, wid = tid >> 6, lane = tid & 63;
  const int g = lane >> 4, lr = lane & 15;
  const size_t base = ((size_t)b * SEQ) * D_MODEL + h * HDIM;
  const size_t vbase = ((size_t)h * HDIM) * NTOK + (size_t)b * SEQ;

#define AST 76
  __shared__ u16 Ks[64 * AST];
  __shared__ u16 Vts[64 * AST];
  __shared__ u16 Ps[128 * AST];

  const int qw = wid * 32;

#pragma unroll
  for (int i = 0; i < 4; ++i) {
    const int ch = tid + 256 * i, row = ch >> 3, j = ch & 7;
    *(bf16x8*)(Ps + row * AST + j * 8) =
        *(const bf16x8*)(Q + base + (size_t)(q0 + row) * D_MODEL + j * 8);
  }
  __syncthreads();
  bf16x8 aq[2][2];
#pragma unroll
  for (int qf = 0; qf < 2; ++qf)
#pragma unroll
    for (int ks = 0; ks < 2; ++ks)
      aq[qf][ks] = *(const bf16x8*)(Ps + (qw + qf * 16 + lr) * AST + ks * 32 + g * 8);

  f32x4 o[2][4] = {};
  float lrun[2][4] = {};

  for (int kv0 = 0; kv0 < SEQ; kv0 += 64) {
    __syncthreads();
#pragma unroll
    for (int i = 0; i < 2; ++i) {
      const int row = (tid >> 3) + i * 32, j = tid & 7;
      *(bf16x8*)(Ks + row * AST + j * 8) =
          *(const bf16x8*)(K + base + (size_t)(kv0 + row) * D_MODEL + j * 8);
      *(bf16x8*)(Vts + row * AST + j * 8) =
          *(const bf16x8*)(Vt + vbase + (size_t)row * NTOK + kv0 + j * 8);
    }
    __syncthreads();

    f32x4 s[2][4] = {};
    __builtin_amdgcn_s_setprio(1);
#pragma unroll
    for (int ks = 0; ks < 2; ++ks)
#pragma unroll
      for (int kf = 0; kf < 4; ++kf) {
        const bf16x8 bk = *(const bf16x8*)(Ks + (kf * 16 + lr) * AST + ks * 32 + g * 8);
#pragma unroll
        for (int qf = 0; qf < 2; ++qf)
          s[qf][kf] = __builtin_amdgcn_mfma_f32_16x16x32_bf16(aq[qf][ks], bk, s[qf][kf], 0, 0, 0);
      }
    __builtin_amdgcn_s_setprio(0);

#pragma unroll
    for (int qf = 0; qf < 2; ++qf)
#pragma unroll
      for (int r = 0; r < 4; ++r) {
        float p0, p1, p2, p3;
        asm("v_exp_f32 %0, %1" : "=v"(p0) : "v"(s[qf][0][r]));
        asm("v_exp_f32 %0, %1" : "=v"(p1) : "v"(s[qf][1][r]));
        asm("v_exp_f32 %0, %1" : "=v"(p2) : "v"(s[qf][2][r]));
        asm("v_exp_f32 %0, %1" : "=v"(p3) : "v"(s[qf][3][r]));
        lrun[qf][r] += (p0 + p1) + (p2 + p3);
        unsigned lo, hi;
        asm("v_cvt_pk_bf16_f32 %0, %1, %2" : "=v"(lo) : "v"(p0), "v"(p1));
        asm("v_cvt_pk_bf16_f32 %0, %1, %2" : "=v"(hi) : "v"(p2), "v"(p3));
        *(uint2*)(Ps + (qw + qf * 16 + 4 * g + r) * AST + lr * 4) = make_uint2(lo, hi);
      }
    asm volatile("s_waitcnt lgkmcnt(0)" ::: "memory");

    __builtin_amdgcn_s_setprio(1);
#pragma unroll
    for (int ks = 0; ks < 2; ++ks) {
      bf16x8 pf[2];
#pragma unroll
      for (int qf = 0; qf < 2; ++qf)
        pf[qf] = *(const bf16x8*)(Ps + (qw + qf * 16 + lr) * AST + ks * 32 + g * 8);
#pragma unroll
      for (int df = 0; df < 4; ++df) {
        const bf16x8 vf = *(const bf16x8*)(Vts + (df * 16 + lr) * AST + ks * 32 + g * 8);
#pragma unroll
        for (int qf = 0; qf < 2; ++qf)
          o[qf][df] = __builtin_amdgcn_mfma_f32_16x16x32_bf16(pf[qf], vf, o[qf][df], 0, 0, 0);
      }
    }
    __builtin_amdgcn_s_setprio(0);
  }

#pragma unroll
  for (int off = 1; off < 16; off <<= 1)
#pragma unroll
    for (int qf = 0; qf < 2; ++qf)
#pragma unroll
      for (int r = 0; r < 4; ++r)
        lrun[qf][r] += __shfl_xor(lrun[qf][r], off);

#pragma unroll
  for (int qf = 0; qf < 2; ++qf)
#pragma unroll
    for (int r = 0; r < 4; ++r) {
      const float rinv = 1.0f / lrun[qf][r];
      const int qrow = q0 + qw + qf * 16 + 4 * g + r;
#pragma unroll
      for (int df = 0; df < 4; ++df)
        ctxo[base + (size_t)qrow * D_MODEL + df * 16 + lr] = f2bf(o[qf][df][r] * rinv);
    }
#undef AST
}

extern "C" void kernel_launch(void* const* d_in, const int* in_sizes, int n_in,
                              void* d_out, int out_size, void* d_ws, size_t ws_size,
                              hipStream_t stream) {
  const float* x  = (const float*)d_in[0];
  const float* Wq = (const float*)d_in[1];
  const float* bq = (const float*)d_in[2];
  const float* Wk = (const float*)d_in[3];
  const float* bk = (const float*)d_in[4];
  const float* Wv = (const float*)d_in[5];
  const float* bv = (const float*)d_in[6];
  const float* Wo = (const float*)d_in[7];
  const float* bo = (const float*)d_in[8];
  const float* W1 = (const float*)d_in[9];
  const float* b1 = (const float*)d_in[10];
  const float* W2 = (const float*)d_in[11];
  const float* b2 = (const float*)d_in[12];
  const float* gamma1 = (const float*)d_in[13];
  const float* beta1  = (const float*)d_in[14];
  const float* gamma2 = (const float*)d_in[15];
  const float* beta2  = (const float*)d_in[16];
  float* out = (float*)d_out;

  const size_t M1 = 1u << 20;  // 1M elems
  u16* w   = (u16*)d_ws;
  u16* WtQ = w;                // [1024][1024]; WtK adjacent -> fused Bt [2048][1024]
  u16* WtV = w + 2 * M1;
  u16* WtO = w + 3 * M1;
  u16* Wt1 = w + 4 * M1;   // [4096][1024]
  u16* Wt2 = w + 8 * M1;   // [1024][4096]
  u16* xn  = w + 12 * M1;
  u16* Qb  = w + 20 * M1;
  u16* Kb  = w + 28 * M1;
  u16* Vtb = w + 36 * M1;  // V^T [1024][8192], kv-permuted within 64-blocks
  u16* ctx = w + 44 * M1;
  u16* hb  = w + 20 * M1;  // h [8192][4096] aliases Q/K/Vt/ctx (dead by FFN1)
  u16* x1b = w + 52 * M1;  // x1 residual in bf16 [8192][1024]

  const dim3 tb(32, 8);
  transpose_cvt4<<<dim3(32, 32, 4), tb, 0, stream>>>(Wq, Wk, Wv, Wo, WtQ);
  transpose_cvt<<<dim3(HIDDEN / 32, D_MODEL / 32), tb, 0, stream>>>(W1, Wt1, D_MODEL, HIDDEN);
  transpose_cvt<<<dim3(D_MODEL / 32, HIDDEN / 32), tb, 0, stream>>>(W2, Wt2, HIDDEN, D_MODEL);

  ln_kernel<<<NTOK, 256, 0, stream>>>(x, gamma1, beta1, xn);

  // fused Q+K projection: Bt = [WtQ;WtK], N=2048 -> 1024 blocks
  gemm64<6, 8, 0><<<1024, 256, 0, stream>>>(xn, WtQ, bq, bk, nullptr, Qb, Kb,
                                            NTOK, 2048, D_MODEL);
  // V^T: C[d][s] = WtV[d][:] . xn[s][:]  (row bias bv[d]), kv-permuted columns
  gemm64<3, 0, 8><<<512, 256, 0, stream>>>(WtV, xn, bv, nullptr, nullptr, Vtb, nullptr,
                                           D_MODEL, NTOK, D_MODEL);

  attn_kernel<<<1024, 256, 0, stream>>>(Qb, Kb, Vtb, ctx);

  // Wo + residual(x) -> x1b (bf16)
  gemm64<7, 8, 0><<<512, 256, 0, stream>>>(ctx, WtO, bo, nullptr, x, x1b, nullptr,
                                           NTOK, D_MODEL, D_MODEL);

  ln_kernel_b<<<NTOK, 256, 0, stream>>>(x1b, gamma2, beta2, xn);

  // FFN1: corrected 8-phase deep pipeline, 256x256 tile -> 512 blocks
  gemm256p<2, 4, 0><<<512, 512, 0, stream>>>(xn, Wt1, b1, nullptr, hb,
                                             NTOK, HIDDEN, D_MODEL);
  // FFN2 + residual(x1b bf16) -> out (f32)
  gemm64<8, 8, 0><<<512, 256, 0, stream>>>(hb, Wt2, b2, nullptr, (const float*)x1b, out,
                                           nullptr, NTOK, D_MODEL, HIDDEN);
}

// Round 17
// 347.337 us; speedup vs baseline: 1.1328x; 1.1328x over previous
//
#include <hip/hip_runtime.h>
#include <stdint.h>

#define D_MODEL 1024
#define HIDDEN  4096
#define SEQ     2048
#define NTOK    8192
#define NHEAD   16
#define HDIM    64

typedef unsigned short u16;
typedef __attribute__((ext_vector_type(8))) __bf16 bf16x8;
typedef __attribute__((ext_vector_type(4))) float f32x4;

__device__ __forceinline__ u16 f2bf(float f) {
  union { float f; unsigned u; } c; c.f = f;
  unsigned u = c.u + 0x7fffu + ((c.u >> 16) & 1u);
  return (u16)(u >> 16);
}

__device__ __forceinline__ float bf2f(u16 u) {
  union { unsigned u; float f; } c; c.u = (unsigned)u << 16;
  return c.f;
}

__device__ __forceinline__ void gload16(const void* g, void* l) {
  __builtin_amdgcn_global_load_lds((const __attribute__((address_space(1))) void*)g,
                                   (__attribute__((address_space(3))) void*)l, 16, 0, 0);
}

// ---------------- weight convert+transpose: 4x [1024][1024] f32 -> [1024][1024] bf16^T ----
__global__ void transpose_cvt4(const float* __restrict__ A0, const float* __restrict__ A1,
                               const float* __restrict__ A2, const float* __restrict__ A3,
                               u16* __restrict__ O) {
  __shared__ float t[32][33];
  const int z = blockIdx.z;
  const float* W = (z == 0) ? A0 : (z == 1) ? A1 : (z == 2) ? A2 : A3;
  u16* Wt = O + ((size_t)z << 20);
  const int k0 = blockIdx.y * 32, n0 = blockIdx.x * 32;
  const int tx = threadIdx.x, ty = threadIdx.y;  // 32 x 8
#pragma unroll
  for (int p = 0; p < 4; ++p)
    t[ty + p * 8][tx] = W[(size_t)(k0 + ty + p * 8) * D_MODEL + n0 + tx];
  __syncthreads();
#pragma unroll
  for (int p = 0; p < 4; ++p) {
    const int n = ty + p * 8;
    Wt[(size_t)(n0 + n) * D_MODEL + k0 + tx] = f2bf(t[tx][n]);
  }
}

// ---------------- weight convert + transpose: W[K][N] f32 -> Wt[N][K] bf16 ----------------
__global__ void transpose_cvt(const float* __restrict__ W, u16* __restrict__ Wt, int K, int N) {
  __shared__ float t[32][33];
  const int k0 = blockIdx.y * 32, n0 = blockIdx.x * 32;
  const int tx = threadIdx.x, ty = threadIdx.y;  // 32 x 8
#pragma unroll
  for (int p = 0; p < 4; ++p)
    t[ty + p * 8][tx] = W[(size_t)(k0 + ty + p * 8) * N + n0 + tx];
  __syncthreads();
#pragma unroll
  for (int p = 0; p < 4; ++p) {
    const int n = ty + p * 8;
    Wt[(size_t)(n0 + n) * K + k0 + tx] = f2bf(t[tx][n]);
  }
}

// ---------------- LayerNorm (f32 in): x f32 [NTOK][D] -> xn bf16 ----------------
__global__ __launch_bounds__(256)
void ln_kernel(const float* __restrict__ x, const float* __restrict__ gamma,
               const float* __restrict__ beta, u16* __restrict__ out) {
  const int row = blockIdx.x;
  const int tid = threadIdx.x;
  const float4 v = ((const float4*)(x + (size_t)row * D_MODEL))[tid];
  float s = v.x + v.y + v.z + v.w;
  float q = v.x * v.x + v.y * v.y + v.z * v.z + v.w * v.w;
#pragma unroll
  for (int o = 32; o > 0; o >>= 1) { s += __shfl_down(s, o); q += __shfl_down(q, o); }
  __shared__ float ps[4], pq[4];
  const int wid = tid >> 6, lane = tid & 63;
  if (lane == 0) { ps[wid] = s; pq[wid] = q; }
  __syncthreads();
  s = ps[0] + ps[1] + ps[2] + ps[3];
  q = pq[0] + pq[1] + pq[2] + pq[3];
  const float mean = s * (1.0f / D_MODEL);
  const float var = q * (1.0f / D_MODEL) - mean * mean;
  const float rstd = rsqrtf(var + 1e-10f);
  const float4 gv = ((const float4*)gamma)[tid];
  const float4 bv = ((const float4*)beta)[tid];
  ushort4 o4;
  o4.x = f2bf((v.x - mean) * rstd * gv.x + bv.x);
  o4.y = f2bf((v.y - mean) * rstd * gv.y + bv.y);
  o4.z = f2bf((v.z - mean) * rstd * gv.z + bv.z);
  o4.w = f2bf((v.w - mean) * rstd * gv.w + bv.w);
  ((ushort4*)(out + (size_t)row * D_MODEL))[tid] = o4;
}

// ---------------- LayerNorm (bf16 in): x1b bf16 [NTOK][D] -> xn bf16 ----------------
__global__ __launch_bounds__(256)
void ln_kernel_b(const u16* __restrict__ x, const float* __restrict__ gamma,
                 const float* __restrict__ beta, u16* __restrict__ out) {
  const int row = blockIdx.x;
  const int tid = threadIdx.x;
  const ushort4 uv = ((const ushort4*)(x + (size_t)row * D_MODEL))[tid];
  const float v0 = bf2f(uv.x), v1 = bf2f(uv.y), v2 = bf2f(uv.z), v3 = bf2f(uv.w);
  float s = v0 + v1 + v2 + v3;
  float q = v0 * v0 + v1 * v1 + v2 * v2 + v3 * v3;
#pragma unroll
  for (int o = 32; o > 0; o >>= 1) { s += __shfl_down(s, o); q += __shfl_down(q, o); }
  __shared__ float ps[4], pq[4];
  const int wid = tid >> 6, lane = tid & 63;
  if (lane == 0) { ps[wid] = s; pq[wid] = q; }
  __syncthreads();
  s = ps[0] + ps[1] + ps[2] + ps[3];
  q = pq[0] + pq[1] + pq[2] + pq[3];
  const float mean = s * (1.0f / D_MODEL);
  const float var = q * (1.0f / D_MODEL) - mean * mean;
  const float rstd = rsqrtf(var + 1e-10f);
  const float4 gv = ((const float4*)gamma)[tid];
  const float4 bv = ((const float4*)beta)[tid];
  ushort4 o4;
  o4.x = f2bf((v0 - mean) * rstd * gv.x + bv.x);
  o4.y = f2bf((v1 - mean) * rstd * gv.y + bv.y);
  o4.z = f2bf((v2 - mean) * rstd * gv.z + bv.z);
  o4.w = f2bf((v3 - mean) * rstd * gv.w + bv.w);
  ((ushort4*)(out + (size_t)row * D_MODEL))[tid] = o4;
}

// ---------------- gemm64: m97 structure, 128x128 tile, BK=64, 4 blocks/CU ----------------
// 256 threads = 4 waves (2m x 2n), per-wave 64x64 (4x4 frags), 32 MFMA / iter.
// Single 32 KB LDS buffer, __syncthreads (compiler vmcnt drain), 8 gload16/thread.
// 8-chunk XOR swizzle (c ^ row&7): fragment ds_read_b128 fully conflict-free.
// EPI 0: bf16 out, col bias.     EPI 1: f32 out += f32 res, col bias.
// EPI 2: gelu(erf)->bf16.  EPI 3: bf16, ROW bias, kv-permuted cols (V^T).
// EPI 6: fused QK dual output.  EPI 7: bf16 out = acc + bias + f32 res.
// EPI 8: f32 out = acc + bias + bf16 res.
template <int EPI, int KPY, int KPX>
__global__ __launch_bounds__(256, 4)
void gemm64(const u16* __restrict__ A, const u16* __restrict__ Bt,
            const float* __restrict__ bias, const float* __restrict__ bias2,
            const float* __restrict__ res, void* __restrict__ outp, void* __restrict__ outp2,
            int M, int N, int K) {
  __shared__ u16 As[128 * 64];
  __shared__ u16 Bs[128 * 64];
  const int tid = threadIdx.x;
  const int wid = tid >> 6, lane = tid & 63;
  const int g = lane >> 4, lr = lane & 15;
  const int wm = (wid & 1) << 6, wn = (wid >> 1) << 6;

  const int xcd = blockIdx.x & 7, l = blockIdx.x >> 3;
  int bx, by;
  if (KPY > 0) { by = xcd * KPY + (l % KPY); bx = l / KPY; }
  else         { bx = xcd * KPX + (l % KPX); by = l / KPX; }
  const int m0 = by * 128, n0 = bx * 128;

  const int NT = K >> 6;

  const int r0 = tid >> 3;
  const int csw = ((tid & 7) ^ (r0 & 7)) << 3;  // pre-swizzled u16 offset within row
  const u16* pA[4];
  const u16* pB[4];
#pragma unroll
  for (int i = 0; i < 4; ++i) {
    pA[i] = A + (size_t)(m0 + r0 + i * 32) * K + csw;
    pB[i] = Bt + (size_t)(n0 + r0 + i * 32) * K + csw;
  }
  const int db = (tid & 192) * 16;  // wave-uniform dest base (bytes)

  f32x4 acc[4][4] = {};

  for (int t = 0; t < NT; ++t) {
    __syncthreads();
#pragma unroll
    for (int i = 0; i < 4; ++i) {
      gload16(pA[i], (char*)As + db + i * 4096);
      gload16(pB[i], (char*)Bs + db + i * 4096);
      pA[i] += 64; pB[i] += 64;
    }
    __syncthreads();

#pragma unroll
    for (int ks = 0; ks < 2; ++ks) {
      bf16x8 af[4], bfr[4];
#pragma unroll
      for (int f = 0; f < 4; ++f) {
        const int ra = wm + f * 16 + lr;
        const int rb = wn + f * 16 + lr;
        const int co = ((ks * 4 + g) ^ (lr & 7)) * 8;
        af[f] = *(const bf16x8*)(As + ra * 64 + co);
        bfr[f] = *(const bf16x8*)(Bs + rb * 64 + co);
      }
      __builtin_amdgcn_s_setprio(1);
#pragma unroll
      for (int mf = 0; mf < 4; ++mf)
#pragma unroll
        for (int nf = 0; nf < 4; ++nf)
          acc[mf][nf] =
              __builtin_amdgcn_mfma_f32_16x16x32_bf16(af[mf], bfr[nf], acc[mf][nf], 0, 0, 0);
      __builtin_amdgcn_s_setprio(0);
    }
  }

  // ---- epilogue ----
#pragma unroll
  for (int mf = 0; mf < 4; ++mf)
#pragma unroll
    for (int nf = 0; nf < 4; ++nf) {
      const int gn = n0 + wn + nf * 16 + lr;
      const int gm = m0 + wm + mf * 16 + 4 * g;
#pragma unroll
      for (int r = 0; r < 4; ++r) {
        const float av = acc[mf][nf][r];
        if (EPI == 0) {
          ((u16*)outp)[(size_t)(gm + r) * N + gn] = f2bf(av + bias[gn]);
        } else if (EPI == 1) {
          const size_t idx = (size_t)(gm + r) * N + gn;
          ((float*)outp)[idx] = av + bias[gn] + res[idx];
        } else if (EPI == 2) {
          const float v = av + bias[gn];
          ((u16*)outp)[(size_t)(gm + r) * N + gn] =
              f2bf(0.5f * v * (1.0f + erff(v * 0.7071067811865475f)));
        } else if (EPI == 3) {
          const int gn_p = (gn & ~63) | ((gn & 15) << 2) | ((gn >> 4) & 3);
          ((u16*)outp)[(size_t)(gm + r) * N + gn_p] = f2bf(av + bias[gm + r]);
        } else if (EPI == 6) {
          const int side = gn >> 10, col = gn & 1023;
          u16* o = (u16*)(side ? outp2 : outp);
          float t_ = av + (side ? bias2[col] : bias[col]);
          if (!side) t_ *= 0.18033688011112042f;
          o[(size_t)(gm + r) * 1024 + col] = f2bf(t_);
        } else if (EPI == 7) {
          const size_t idx = (size_t)(gm + r) * N + gn;
          ((u16*)outp)[idx] = f2bf(av + bias[gn] + res[idx]);
        } else {  // EPI 8: f32 out = acc + bias + bf16 residual
          const size_t idx = (size_t)(gm + r) * N + gn;
          ((float*)outp)[idx] = av + bias[gn] + bf2f(((const u16*)res)[idx]);
        }
      }
    }
}

// ---------------- flash attention v5 (round-11/13 proven, 91.7 us) ----------------
// Q bf16 (pre-scaled by 0.125*log2e); K bf16; Vt bf16 [D][NTOK] kv-permuted; ctx bf16.
// No-max softmax in base 2.  Stride 76 (2-way banks).  XCD-affine bh mapping.
__global__ __launch_bounds__(256, 4)
void attn_kernel(const u16* __restrict__ Q, const u16* __restrict__ K,
                 const u16* __restrict__ Vt, u16* __restrict__ ctxo) {
  const int L = blockIdx.x;
  const int q0 = ((L >> 3) & 15) * 128;
  const int bh = ((L >> 7) << 3) | (L & 7);
  const int b = bh >> 4, h = bh & 15;
  const int tid = threadIdx.x, wid = tid >> 6, lane = tid & 63;
  const int g = lane >> 4, lr = lane & 15;
  const size_t base = ((size_t)b * SEQ) * D_MODEL + h * HDIM;
  const size_t vbase = ((size_t)h * HDIM) * NTOK + (size_t)b * SEQ;

#define AST 76
  __shared__ u16 Ks[64 * AST];
  __shared__ u16 Vts[64 * AST];
  __shared__ u16 Ps[128 * AST];

  const int qw = wid * 32;

#pragma unroll
  for (int i = 0; i < 4; ++i) {
    const int ch = tid + 256 * i, row = ch >> 3, j = ch & 7;
    *(bf16x8*)(Ps + row * AST + j * 8) =
        *(const bf16x8*)(Q + base + (size_t)(q0 + row) * D_MODEL + j * 8);
  }
  __syncthreads();
  bf16x8 aq[2][2];
#pragma unroll
  for (int qf = 0; qf < 2; ++qf)
#pragma unroll
    for (int ks = 0; ks < 2; ++ks)
      aq[qf][ks] = *(const bf16x8*)(Ps + (qw + qf * 16 + lr) * AST + ks * 32 + g * 8);

  f32x4 o[2][4] = {};
  float lrun[2][4] = {};

  for (int kv0 = 0; kv0 < SEQ; kv0 += 64) {
    __syncthreads();
#pragma unroll
    for (int i = 0; i < 2; ++i) {
      const int row = (tid >> 3) + i * 32, j = tid & 7;
      *(bf16x8*)(Ks + row * AST + j * 8) =
          *(const bf16x8*)(K + base + (size_t)(kv0 + row) * D_MODEL + j * 8);
      *(bf16x8*)(Vts + row * AST + j * 8) =
          *(const bf16x8*)(Vt + vbase + (size_t)row * NTOK + kv0 + j * 8);
    }
    __syncthreads();

    f32x4 s[2][4] = {};
    __builtin_amdgcn_s_setprio(1);
#pragma unroll
    for (int ks = 0; ks < 2; ++ks)
#pragma unroll
      for (int kf = 0; kf < 4; ++kf) {
        const bf16x8 bk = *(const bf16x8*)(Ks + (kf * 16 + lr) * AST + ks * 32 + g * 8);
#pragma unroll
        for (int qf = 0; qf < 2; ++qf)
          s[qf][kf] = __builtin_amdgcn_mfma_f32_16x16x32_bf16(aq[qf][ks], bk, s[qf][kf], 0, 0, 0);
      }
    __builtin_amdgcn_s_setprio(0);

#pragma unroll
    for (int qf = 0; qf < 2; ++qf)
#pragma unroll
      for (int r = 0; r < 4; ++r) {
        float p0, p1, p2, p3;
        asm("v_exp_f32 %0, %1" : "=v"(p0) : "v"(s[qf][0][r]));
        asm("v_exp_f32 %0, %1" : "=v"(p1) : "v"(s[qf][1][r]));
        asm("v_exp_f32 %0, %1" : "=v"(p2) : "v"(s[qf][2][r]));
        asm("v_exp_f32 %0, %1" : "=v"(p3) : "v"(s[qf][3][r]));
        lrun[qf][r] += (p0 + p1) + (p2 + p3);
        unsigned lo, hi;
        asm("v_cvt_pk_bf16_f32 %0, %1, %2" : "=v"(lo) : "v"(p0), "v"(p1));
        asm("v_cvt_pk_bf16_f32 %0, %1, %2" : "=v"(hi) : "v"(p2), "v"(p3));
        *(uint2*)(Ps + (qw + qf * 16 + 4 * g + r) * AST + lr * 4) = make_uint2(lo, hi);
      }
    asm volatile("s_waitcnt lgkmcnt(0)" ::: "memory");

    __builtin_amdgcn_s_setprio(1);
#pragma unroll
    for (int ks = 0; ks < 2; ++ks) {
      bf16x8 pf[2];
#pragma unroll
      for (int qf = 0; qf < 2; ++qf)
        pf[qf] = *(const bf16x8*)(Ps + (qw + qf * 16 + lr) * AST + ks * 32 + g * 8);
#pragma unroll
      for (int df = 0; df < 4; ++df) {
        const bf16x8 vf = *(const bf16x8*)(Vts + (df * 16 + lr) * AST + ks * 32 + g * 8);
#pragma unroll
        for (int qf = 0; qf < 2; ++qf)
          o[qf][df] = __builtin_amdgcn_mfma_f32_16x16x32_bf16(pf[qf], vf, o[qf][df], 0, 0, 0);
      }
    }
    __builtin_amdgcn_s_setprio(0);
  }

#pragma unroll
  for (int off = 1; off < 16; off <<= 1)
#pragma unroll
    for (int qf = 0; qf < 2; ++qf)
#pragma unroll
      for (int r = 0; r < 4; ++r)
        lrun[qf][r] += __shfl_xor(lrun[qf][r], off);

#pragma unroll
  for (int qf = 0; qf < 2; ++qf)
#pragma unroll
    for (int r = 0; r < 4; ++r) {
      const float rinv = 1.0f / lrun[qf][r];
      const int qrow = q0 + qw + qf * 16 + 4 * g + r;
#pragma unroll
      for (int df = 0; df < 4; ++df)
        ctxo[base + (size_t)qrow * D_MODEL + df * 16 + lr] = f2bf(o[qf][df][r] * rinv);
    }
#undef AST
}

extern "C" void kernel_launch(void* const* d_in, const int* in_sizes, int n_in,
                              void* d_out, int out_size, void* d_ws, size_t ws_size,
                              hipStream_t stream) {
  const float* x  = (const float*)d_in[0];
  const float* Wq = (const float*)d_in[1];
  const float* bq = (const float*)d_in[2];
  const float* Wk = (const float*)d_in[3];
  const float* bk = (const float*)d_in[4];
  const float* Wv = (const float*)d_in[5];
  const float* bv = (const float*)d_in[6];
  const float* Wo = (const float*)d_in[7];
  const float* bo = (const float*)d_in[8];
  const float* W1 = (const float*)d_in[9];
  const float* b1 = (const float*)d_in[10];
  const float* W2 = (const float*)d_in[11];
  const float* b2 = (const float*)d_in[12];
  const float* gamma1 = (const float*)d_in[13];
  const float* beta1  = (const float*)d_in[14];
  const float* gamma2 = (const float*)d_in[15];
  const float* beta2  = (const float*)d_in[16];
  float* out = (float*)d_out;

  const size_t M1 = 1u << 20;  // 1M elems
  u16* w   = (u16*)d_ws;
  u16* WtQ = w;                // [1024][1024]; WtK adjacent -> fused Bt [2048][1024]
  u16* WtV = w + 2 * M1;
  u16* WtO = w + 3 * M1;
  u16* Wt1 = w + 4 * M1;   // [4096][1024]
  u16* Wt2 = w + 8 * M1;   // [1024][4096]
  u16* xn  = w + 12 * M1;
  u16* Qb  = w + 20 * M1;
  u16* Kb  = w + 28 * M1;
  u16* Vtb = w + 36 * M1;  // V^T [1024][8192], kv-permuted within 64-blocks
  u16* ctx = w + 44 * M1;
  u16* hb  = w + 20 * M1;  // h [8192][4096] aliases Q/K/Vt/ctx (dead by FFN1)
  u16* x1b = w + 52 * M1;  // x1 residual in bf16 [8192][1024]

  const dim3 tb(32, 8);
  transpose_cvt4<<<dim3(32, 32, 4), tb, 0, stream>>>(Wq, Wk, Wv, Wo, WtQ);
  transpose_cvt<<<dim3(HIDDEN / 32, D_MODEL / 32), tb, 0, stream>>>(W1, Wt1, D_MODEL, HIDDEN);
  transpose_cvt<<<dim3(D_MODEL / 32, HIDDEN / 32), tb, 0, stream>>>(W2, Wt2, HIDDEN, D_MODEL);

  ln_kernel<<<NTOK, 256, 0, stream>>>(x, gamma1, beta1, xn);

  // fused Q+K projection: Bt = [WtQ;WtK], N=2048 -> 1024 blocks
  gemm64<6, 8, 0><<<1024, 256, 0, stream>>>(xn, WtQ, bq, bk, nullptr, Qb, Kb,
                                            NTOK, 2048, D_MODEL);
  // V^T: C[d][s] = WtV[d][:] . xn[s][:]  (row bias bv[d]), kv-permuted columns
  gemm64<3, 0, 8><<<512, 256, 0, stream>>>(WtV, xn, bv, nullptr, nullptr, Vtb, nullptr,
                                           D_MODEL, NTOK, D_MODEL);

  attn_kernel<<<1024, 256, 0, stream>>>(Qb, Kb, Vtb, ctx);

  // Wo + residual(x f32) -> x1b (bf16)
  gemm64<7, 8, 0><<<512, 256, 0, stream>>>(ctx, WtO, bo, nullptr, x, x1b, nullptr,
                                           NTOK, D_MODEL, D_MODEL);

  ln_kernel_b<<<NTOK, 256, 0, stream>>>(x1b, gamma2, beta2, xn);

  // FFN1: gemm64, full chip
  gemm64<2, 8, 0><<<2048, 256, 0, stream>>>(xn, Wt1, b1, nullptr, nullptr, hb, nullptr,
                                            NTOK, HIDDEN, D_MODEL);
  // FFN2 + residual(x1b bf16) -> out (f32)
  gemm64<8, 8, 0><<<512, 256, 0, stream>>>(hb, Wt2, b2, nullptr, (const float*)x1b, out,
                                           nullptr, NTOK, D_MODEL, HIDDEN);
}